// Round 1
// baseline (892.588 us; speedup 1.0000x reference)
//
#include <hip/hip_runtime.h>

typedef unsigned int uint32;

__global__ __launch_bounds__(256) void
spike_tanh_kernel(const uint4* __restrict__ in, uint4* __restrict__ out, int n_elems) {
    const int stride = gridDim.x * blockDim.x;
    for (int i = blockIdx.x * blockDim.x + threadIdx.x; i < n_elems; i += stride) {
        // ---- assemble 32 pulses (MSB first) into a uint32 ----
        // pulse is 0.0f (0x00000000) or 1.0f (0x3F800000): bit set iff word nonzero
        const uint4* p = in + (size_t)i * 8;
        uint32 u = 0u;
#pragma unroll
        for (int k = 0; k < 8; ++k) {
            uint4 b = p[k];
            u = (u << 4) | ((b.x ? 8u : 0u) | (b.y ? 4u : 0u) |
                            (b.z ? 2u : 0u) | (b.w ? 1u : 0u));
        }
        float v;
        __builtin_memcpy(&v, &u, 4);

        // ---- exact FP64 op sequence of the reference ----
        double e2x = exp(2.0 * (double)v);
        double t64 = (e2x - 1.0) / (e2x + 1.0);
        float r = (float)t64;

        uint32 ru;
        __builtin_memcpy(&ru, &r, 4);

        // ---- emit 32 pulses, MSB first ----
        uint4* q = out + (size_t)i * 8;
#pragma unroll
        for (int k = 0; k < 8; ++k) {
            uint4 o;
            o.x = (ru & 0x80000000u) ? 0x3F800000u : 0u;
            o.y = (ru & 0x40000000u) ? 0x3F800000u : 0u;
            o.z = (ru & 0x20000000u) ? 0x3F800000u : 0u;
            o.w = (ru & 0x10000000u) ? 0x3F800000u : 0u;
            ru <<= 4;
            q[k] = o;
        }
    }
}

extern "C" void kernel_launch(void* const* d_in, const int* in_sizes, int n_in,
                              void* d_out, int out_size, void* d_ws, size_t ws_size,
                              hipStream_t stream) {
    (void)n_in; (void)d_ws; (void)ws_size; (void)out_size;
    const int n_elems = in_sizes[0] / 32;           // 4,194,304 scalars
    const uint4* in  = (const uint4*)d_in[0];
    uint4*       out = (uint4*)d_out;

    const int block = 256;
    int grid = (n_elems + block - 1) / block;
    if (grid > 2048) grid = 2048;                   // grid-stride the rest
    spike_tanh_kernel<<<grid, block, 0, stream>>>(in, out, n_elems);
}

// Round 2
// 844.696 us; speedup vs baseline: 1.0567x; 1.0567x over previous
//
#include <hip/hip_runtime.h>

typedef unsigned int uint32;

__global__ __launch_bounds__(256) void
spike_tanh_kernel(const uint4* __restrict__ in, uint4* __restrict__ out, long n_vec4) {
    const long stride = (long)gridDim.x * blockDim.x;
    const int pos   = threadIdx.x & 7;     // position within the 8-lane group
    const int shift = 4 * (7 - pos);       // MSB-first nibble position

    for (long i = (long)blockIdx.x * blockDim.x + threadIdx.x; i < n_vec4; i += stride) {
        // ---- coalesced load: lane i reads uint4 i (16 B/lane, wave-contiguous) ----
        uint4 b = in[i];
        // pulse word is 0x3F800000 (1.0f) or 0x00000000: bit set iff word nonzero
        uint32 nib = (b.x ? 8u : 0u) | (b.y ? 4u : 0u) |
                     (b.z ? 2u : 0u) | (b.w ? 1u : 0u);
        uint32 u = nib << shift;

        // ---- OR-butterfly across the 8-lane group: all 8 lanes get the full word ----
        u |= __shfl_xor(u, 1);
        u |= __shfl_xor(u, 2);
        u |= __shfl_xor(u, 4);

        // ---- exact FP64 op sequence of the reference (redundant per lane: free) ----
        float v = __uint_as_float(u);
        double e2x = exp(2.0 * (double)v);
        double t64 = (e2x - 1.0) / (e2x + 1.0);
        float r = (float)t64;
        uint32 ru = __float_as_uint(r);

        // ---- each lane emits its own 4 output pulses, coalesced store ----
        uint32 onib = (ru >> shift) & 0xFu;
        uint4 o;
        o.x = (onib & 8u) ? 0x3F800000u : 0u;
        o.y = (onib & 4u) ? 0x3F800000u : 0u;
        o.z = (onib & 2u) ? 0x3F800000u : 0u;
        o.w = (onib & 1u) ? 0x3F800000u : 0u;
        out[i] = o;
    }
}

extern "C" void kernel_launch(void* const* d_in, const int* in_sizes, int n_in,
                              void* d_out, int out_size, void* d_ws, size_t ws_size,
                              hipStream_t stream) {
    (void)n_in; (void)d_ws; (void)ws_size; (void)out_size;
    const long n_vec4 = (long)in_sizes[0] / 4;      // 33,554,432 uint4s
    const uint4* in  = (const uint4*)d_in[0];
    uint4*       out = (uint4*)d_out;

    const int block = 256;
    long grid_l = (n_vec4 + block - 1) / block;
    int grid = grid_l > 2048 ? 2048 : (int)grid_l;  // grid-stride the rest
    spike_tanh_kernel<<<grid, block, 0, stream>>>(in, out, n_vec4);
}

// Round 3
// 827.792 us; speedup vs baseline: 1.0783x; 1.0204x over previous
//
#include <hip/hip_runtime.h>

typedef unsigned int uint32;
typedef unsigned int v4u __attribute__((ext_vector_type(4)));

__device__ __forceinline__ uint32 assemble_word(v4u b, int shift) {
    // pulse word is exactly 0x3F800000 (1.0f) or 0x00000000; bit 29 distinguishes.
    uint32 nib = ((b.x >> 26) & 8u) | ((b.y >> 27) & 4u) |
                 ((b.z >> 28) & 2u) | ((b.w >> 29) & 1u);
    uint32 u = nib << shift;
    // OR-butterfly across the 8-lane group: all 8 lanes get the full 32-bit word
    u |= __shfl_xor(u, 1);
    u |= __shfl_xor(u, 2);
    u |= __shfl_xor(u, 4);
    return u;
}

__device__ __forceinline__ uint32 tanh_bits(uint32 u) {
    // exact FP64 op sequence of the reference
    float v = __uint_as_float(u);
    double e2x = exp(2.0 * (double)v);
    double t64 = (e2x - 1.0) / (e2x + 1.0);
    float r = (float)t64;
    return __float_as_uint(r);
}

__device__ __forceinline__ v4u expand_nibble(uint32 ru, int shift) {
    uint32 onib = (ru >> shift) & 0xFu;
    v4u o;
    o.x = (onib & 8u) ? 0x3F800000u : 0u;
    o.y = (onib & 4u) ? 0x3F800000u : 0u;
    o.z = (onib & 2u) ? 0x3F800000u : 0u;
    o.w = (onib & 1u) ? 0x3F800000u : 0u;
    return o;
}

__global__ __launch_bounds__(256) void
spike_tanh_kernel(const v4u* __restrict__ in, v4u* __restrict__ out, int n_vec4) {
    const int stride = gridDim.x * blockDim.x;   // v4u elements per sweep
    const int shift  = 4 * (7 - (threadIdx.x & 7));  // MSB-first nibble of this lane

    for (int i = blockIdx.x * blockDim.x + threadIdx.x; i < n_vec4; i += 2 * stride) {
        const int i1 = i + stride;
        const bool has2 = (i1 < n_vec4);

        // issue both independent loads up front (2x MLP)
        v4u a = __builtin_nontemporal_load(in + i);
        v4u b = has2 ? __builtin_nontemporal_load(in + i1) : a;

        uint32 ua = assemble_word(a, shift);
        uint32 ub = assemble_word(b, shift);

        uint32 ra = tanh_bits(ua);
        uint32 rb = tanh_bits(ub);

        __builtin_nontemporal_store(expand_nibble(ra, shift), out + i);
        if (has2) __builtin_nontemporal_store(expand_nibble(rb, shift), out + i1);
    }
}

extern "C" void kernel_launch(void* const* d_in, const int* in_sizes, int n_in,
                              void* d_out, int out_size, void* d_ws, size_t ws_size,
                              hipStream_t stream) {
    (void)n_in; (void)d_ws; (void)ws_size; (void)out_size;
    const int n_vec4 = in_sizes[0] / 4;             // 33,554,432 uint4s
    const v4u* in  = (const v4u*)d_in[0];
    v4u*       out = (v4u*)d_out;

    const int block = 256;
    long grid_l = ((long)n_vec4 + block - 1) / block;
    int grid = grid_l > 2048 ? 2048 : (int)grid_l;  // 2048 blocks = 32 waves/CU, grid-stride
    spike_tanh_kernel<<<grid, block, 0, stream>>>(in, out, n_vec4);
}